// Round 4
// baseline (14202.242 us; speedup 1.0000x reference)
//
#include <hip/hip_runtime.h>

typedef unsigned short u16;

#define R3 32768
#define NPTS 16384

__device__ __forceinline__ float b2f(u16 u) {
  union { unsigned int i; float f; } v; v.i = ((unsigned int)u) << 16; return v.f;
}
__device__ __forceinline__ u16 f2b(float f) {
  union { float f; unsigned int i; } v; v.f = f;
  unsigned int x = v.i;
  return (u16)((x + 0x7fffu + ((x >> 16) & 1u)) >> 16);
}
__device__ __forceinline__ float silu(float x) {
  return x / (1.f + __expf(-x));
}

// ---- K_wT: w[o][i][27] -> wT[t][i][o] fp32 (both convs) -------------------
__global__ void transform_w(const float* __restrict__ w1, const float* __restrict__ w2,
                            float* __restrict__ wT1, float* __restrict__ wT2) {
  int e = blockIdx.x * 256 + threadIdx.x;
  if (e < 27 * 64 * 128) {   // wT1[(t*64+i)*128+o]
    int t = e / (64 * 128), i = (e / 128) % 64, o = e % 128;
    wT1[e] = w1[(o * 64 + i) * 27 + t];
  }
  if (e < 27 * 128 * 128) {  // wT2[(t*128+i)*128+o]
    int t = e / (128 * 128), i = (e / 128) % 128, o = e % 128;
    wT2[e] = w2[(o * 128 + i) * 27 + t];
  }
}

// ---- K_pvox ---------------------------------------------------------------
__global__ void calc_pvox(const float* __restrict__ coords, int* __restrict__ pvox) {
  int t = blockIdx.x * 256 + threadIdx.x;  // < 4*16384
  if (t >= 4 * NPTS) return;
  const float* cp = coords + (size_t)t * 3;
  int ix = min(max((int)floorf(cp[0] * 32.f), 0), 31);
  int iy = min(max((int)floorf(cp[1] * 32.f), 0), 31);
  int iz = min(max((int)floorf(cp[2] * 32.f), 0), 31);
  pvox[t] = (ix * 32 + iy) * 32 + iz;
}

// ---- K_scatter: fp32 atomics into Gsum[b][vox][64] + counts ---------------
__global__ void __launch_bounds__(256)
scatter_feats(const float* __restrict__ features, const int* __restrict__ pvox,
              float* __restrict__ Gsum, float* __restrict__ Gcnt) {
  size_t t = (size_t)blockIdx.x * 256 + threadIdx.x;  // < 4 * 2^20
  int n  = (int)(t & 16383);
  int ci = (int)((t >> 14) & 63);
  int bi = (int)(t >> 20);
  int v = pvox[bi * NPTS + n];
  float val = features[t];  // features flat [b][ci][n] index == t
  atomicAdd(&Gsum[((size_t)bi * R3 + v) * 64 + ci], val);
  if (ci == 0) atomicAdd(&Gcnt[bi * R3 + v], 1.f);
}

// ---- K_finalize: X1 = Gsum / max(cnt,1), in place -------------------------
__global__ void __launch_bounds__(256)
finalize_grid(float* __restrict__ Gsum, const float* __restrict__ Gcnt) {
  size_t t = (size_t)blockIdx.x * 256 + threadIdx.x;  // < 4*32768*64
  float c = Gcnt[t >> 6];
  Gsum[t] = Gsum[t] / fmaxf(c, 1.f);
}

// ---- naive conv3x3x3 + per-voxel GroupNorm(16) + SiLU, fully fused --------
// X fp32 [b][vox][CI], wT fp32 [t][i][128], out 128 channels.
// One thread = one voxel x one group of 16 consecutive channels.
// OUT_BF16: store u16 bf16, else fp32.
template<int CI, bool OUT_BF16>
__global__ void __launch_bounds__(256)
conv_naive(const float* __restrict__ X, const float* __restrict__ wT,
           const float* __restrict__ bias, const float* __restrict__ gamma,
           const float* __restrict__ beta, float* __restrict__ Yf,
           u16* __restrict__ Yb) {
  // grid: 4096 = 4b * 32x * 32y; block 256 = 32z * 8 groups
  const int bi = blockIdx.x >> 10;
  const int x = (blockIdx.x >> 5) & 31;
  const int y = blockIdx.x & 31;
  const int z = threadIdx.x & 31;
  const int og = threadIdx.x >> 5;     // group 0..7
  const int co0 = og * 16;

  float acc[16];
#pragma unroll
  for (int q = 0; q < 16; ++q) acc[q] = bias[co0 + q];

  for (int t = 0; t < 27; ++t) {
    int dx = t / 9 - 1, dy = (t / 3) % 3 - 1, dz = t % 3 - 1;
    int xs = x + dx, ys = y + dy, zs = z + dz;
    if (xs < 0 || xs > 31 || ys < 0 || ys > 31 || zs < 0 || zs > 31) continue;
    const float* xp = X + ((size_t)bi * R3 + (size_t)((xs * 32 + ys) * 32 + zs)) * CI;
    const float* wp = wT + (size_t)t * CI * 128 + co0;
    for (int i = 0; i < CI; ++i) {
      float xv = xp[i];
      const float* wr = wp + i * 128;
#pragma unroll
      for (int q = 0; q < 16; ++q) acc[q] = fmaf(xv, wr[q], acc[q]);
    }
  }

  // per-voxel GroupNorm over these 16 channels (two-pass) + SiLU
  float mu = 0.f;
#pragma unroll
  for (int q = 0; q < 16; ++q) mu += acc[q];
  mu *= 0.0625f;
  float var = 0.f;
#pragma unroll
  for (int q = 0; q < 16; ++q) { float d = acc[q] - mu; var = fmaf(d, d, var); }
  var *= 0.0625f;
  float rs = rsqrtf(var + 1e-5f);

  size_t row = (size_t)bi * R3 + (size_t)((x * 32 + y) * 32 + z);
  if (OUT_BF16) {
    u16 outv[16];
#pragma unroll
    for (int q = 0; q < 16; ++q) {
      float xn = (acc[q] - mu) * rs * gamma[co0 + q] + beta[co0 + q];
      outv[q] = f2b(silu(xn));
    }
    *(uint4*)(Yb + row * 128 + co0)     = *(uint4*)(outv);
    *(uint4*)(Yb + row * 128 + co0 + 8) = *(uint4*)(outv + 8);
  } else {
    float* yp = Yf + row * 128 + co0;
#pragma unroll
    for (int q = 0; q < 16; ++q) {
      float xn = (acc[q] - mu) * rs * gamma[co0 + q] + beta[co0 + q];
      yp[q] = silu(xn);
    }
  }
}

// ---- K_mlp: pf[b][n][co] = silu-less raw (bias added), bf16 ---------------
__global__ void __launch_bounds__(128)
mlp_naive(const float* __restrict__ features, const float* __restrict__ mw,
          const float* __restrict__ mb, u16* __restrict__ pf) {
  const int co = threadIdx.x;          // 0..127
  const int n = blockIdx.x & 16383;
  const int bi = blockIdx.x >> 14;
  float acc = mb[co];
  const float* fp = features + (size_t)bi * 64 * NPTS + n;
  const float* wp = mw + co * 64;
  for (int i = 0; i < 64; ++i) acc = fmaf(fp[(size_t)i * NPTS], wp[i], acc);
  pf[((size_t)bi * NPTS + n) * 128 + co] = f2b(acc);
}

// ---- K_stats: per (b,group) sum/sumsq over pf -----------------------------
__global__ void __launch_bounds__(256)
point_stats(const u16* __restrict__ pf, float* __restrict__ stats) {
  __shared__ float sl[256], ql[256];
  const int bi = blockIdx.x >> 3;
  const int g = blockIdx.x & 7;
  float s = 0.f, sq = 0.f;
  for (int n = threadIdx.x; n < NPTS; n += 256) {
    const u16* pp = pf + ((size_t)bi * NPTS + n) * 128 + g * 16;
#pragma unroll
    for (int j = 0; j < 16; ++j) {
      float v = b2f(pp[j]);
      s += v; sq = fmaf(v, v, sq);
    }
  }
  sl[threadIdx.x] = s; ql[threadIdx.x] = sq;
  __syncthreads();
  for (int off = 128; off > 0; off >>= 1) {
    if (threadIdx.x < off) {
      sl[threadIdx.x] += sl[threadIdx.x + off];
      ql[threadIdx.x] += ql[threadIdx.x + off];
    }
    __syncthreads();
  }
  if (threadIdx.x == 0) {
    stats[(bi * 8 + g) * 2 + 0] = sl[0];
    stats[(bi * 8 + g) * 2 + 1] = ql[0];
  }
}

// ---- K_final: devox gather + point-branch GN/SiLU + add -------------------
__global__ void __launch_bounds__(256)
final_fuse(const float* __restrict__ coords, const u16* __restrict__ H,
           const u16* __restrict__ pf, const float* __restrict__ stats,
           const float* __restrict__ gg, const float* __restrict__ gb,
           float* __restrict__ out) {
  __shared__ float trans[64][130];
  const int tid = threadIdx.x;
  const int wave = tid >> 6, lane = tid & 63;
  const int bi = blockIdx.x >> 8;
  const int p0 = (blockIdx.x & 255) << 6;
  const int co = lane * 2;
  const int grp = co >> 4;
  const float cntInv = 1.f / (16.f * 16384.f);
  float S  = stats[(bi * 8 + grp) * 2 + 0];
  float SS = stats[(bi * 8 + grp) * 2 + 1];
  float mu = S * cntInv;
  float var = SS * cntInv - mu * mu;
  float rs = rsqrtf(var + 1e-5f);
  float g0 = gg[co], g1 = gg[co + 1], b0 = gb[co], b1 = gb[co + 1];

  for (int pi = 0; pi < 16; ++pi) {
    int pl = wave * 16 + pi;
    int p = p0 + pl;
    const float* cp = coords + ((size_t)bi * NPTS + p) * 3;
    float cx = cp[0] * 32.f, cy = cp[1] * 32.f, cz = cp[2] * 32.f;
    float fx = floorf(cx), fy = floorf(cy), fz = floorf(cz);
    int ix = min(max((int)fx, 0), 31);
    int iy = min(max((int)fy, 0), 31);
    int iz = min(max((int)fz, 0), 31);
    float rx = cx - fx, ry = cy - fy, rz = cz - fz;
    int hx = min(ix + 1, 31), hy = min(iy + 1, 31), hz = min(iz + 1, 31);
    float a0 = 0.f, a1 = 0.f;
#pragma unroll
    for (int k = 0; k < 8; ++k) {
      int xb = k >> 2, yb = (k >> 1) & 1, zb = k & 1;
      float w = (xb ? rx : 1.f - rx) * (yb ? ry : 1.f - ry) * (zb ? rz : 1.f - rz);
      int vi = ((xb ? hx : ix) * 32 + (yb ? hy : iy)) * 32 + (zb ? hz : iz);
      unsigned hv = *(const unsigned*)(H + ((size_t)bi * R3 + vi) * 128 + co);
      a0 += w * b2f((u16)(hv & 0xffff));
      a1 += w * b2f((u16)(hv >> 16));
    }
    unsigned pv = *(const unsigned*)(pf + ((size_t)bi * NPTS + p) * 128 + co);
    float q0 = (b2f((u16)(pv & 0xffff)) - mu) * rs * g0 + b0;
    float q1 = (b2f((u16)(pv >> 16)) - mu) * rs * g1 + b1;
    trans[pl][co]     = silu(q0) + a0;
    trans[pl][co + 1] = silu(q1) + a1;
  }
  __syncthreads();
  for (int e = tid; e < 8192; e += 256) {
    int c = e >> 6, pp = e & 63;
    out[((size_t)bi * 128 + c) * NPTS + p0 + pp] = trans[pp][c];
  }
}

// ---- host -----------------------------------------------------------------
extern "C" void kernel_launch(void* const* d_in, const int* in_sizes, int n_in,
                              void* d_out, int out_size, void* d_ws, size_t ws_size,
                              hipStream_t stream) {
  const float* coords   = (const float*)d_in[0];
  const float* features = (const float*)d_in[1];
  const float* conv1_w  = (const float*)d_in[2];
  const float* conv1_b  = (const float*)d_in[3];
  const float* gn1_g    = (const float*)d_in[4];
  const float* gn1_b    = (const float*)d_in[5];
  const float* conv2_w  = (const float*)d_in[6];
  const float* conv2_b  = (const float*)d_in[7];
  const float* gn2_g    = (const float*)d_in[8];
  const float* gn2_b    = (const float*)d_in[9];
  const float* mlp_w    = (const float*)d_in[10];
  const float* mlp_b    = (const float*)d_in[11];
  const float* gnp_g    = (const float*)d_in[12];
  const float* gnp_b    = (const float*)d_in[13];

  char* ws = (char*)d_ws;
  // layout (bytes):
  float* Gsum = (float*)(ws + 0);            // 33554432 fp32 [b][vox][64] -> X1 in place; H bf16 aliases after conv1
  u16*   H    = (u16*)(ws + 0);              // 16777216 bf16 [b][vox][128]
  float* X2   = (float*)(ws + 33554432);     // 67108864 fp32 [b][vox][128] -> 100663296
  float* Gcnt = (float*)(ws + 100663296);    // 524288   -> 101187584
  float* stats = (float*)(ws + 101187584);   // 4096     -> 101191680
  int*   pvox = (int*)(ws + 101191680);      // 262144   -> 101453824
  u16*   pf   = (u16*)(ws + 101453824);      // 16777216 -> 118231040
  float* wT1  = (float*)(ws + 118231040);    // 884736   -> 119115776
  float* wT2  = (float*)(ws + 119115776);    // 1769472  -> 120885248  (~120.9 MB total)

  hipMemsetAsync(ws, 0, 33554432, stream);                    // Gsum
  hipMemsetAsync(ws + 100663296, 0, 524288 + 4096, stream);   // Gcnt + stats

  transform_w<<<(27 * 128 * 128 + 255) / 256, 256, 0, stream>>>(conv1_w, conv2_w, wT1, wT2);
  calc_pvox<<<(4 * NPTS + 255) / 256, 256, 0, stream>>>(coords, pvox);
  scatter_feats<<<16384, 256, 0, stream>>>(features, pvox, Gsum, Gcnt);
  finalize_grid<<<32768, 256, 0, stream>>>(Gsum, Gcnt);
  conv_naive<64, false><<<4096, 256, 0, stream>>>(
      Gsum, wT1, conv1_b, gn1_g, gn1_b, X2, (u16*)nullptr);
  mlp_naive<<<4 * NPTS, 128, 0, stream>>>(features, mlp_w, mlp_b, pf);
  point_stats<<<32, 256, 0, stream>>>(pf, stats);
  conv_naive<128, true><<<4096, 256, 0, stream>>>(
      X2, wT2, conv2_b, gn2_g, gn2_b, (float*)nullptr, H);
  final_fuse<<<1024, 256, 0, stream>>>(coords, H, pf, stats, gnp_g, gnp_b,
                                       (float*)d_out);
}

// Round 6
// 5570.166 us; speedup vs baseline: 2.5497x; 2.5497x over previous
//
#include <hip/hip_runtime.h>

typedef unsigned short u16;

#define R3 32768
#define NPTS 16384

__device__ __forceinline__ float b2f(u16 u) {
  union { unsigned int i; float f; } v; v.i = ((unsigned int)u) << 16; return v.f;
}
__device__ __forceinline__ u16 f2b(float f) {
  union { float f; unsigned int i; } v; v.f = f;
  unsigned int x = v.i;
  return (u16)((x + 0x7fffu + ((x >> 16) & 1u)) >> 16);
}
__device__ __forceinline__ void split2(float x, u16& h, u16& l) {
  h = f2b(x); l = f2b(x - b2f(h));
}
__device__ __forceinline__ float silu(float x) {
  return x / (1.f + __expf(-x));
}

// ---- K_wT: w[o][i][27] -> wT[t][i][o] fp32 (PROVEN in round 4) ------------
__global__ void transform_w(const float* __restrict__ w1, const float* __restrict__ w2,
                            float* __restrict__ wT1, float* __restrict__ wT2) {
  int e = blockIdx.x * 256 + threadIdx.x;
  if (e < 27 * 64 * 128) {   // wT1[(t*64+i)*128+o]
    int t = e / (64 * 128), i = (e / 128) % 64, o = e % 128;
    wT1[e] = w1[(o * 64 + i) * 27 + t];
  }
  if (e < 27 * 128 * 128) {  // wT2[(t*128+i)*128+o]
    int t = e / (128 * 128), i = (e / 128) % 128, o = e % 128;
    wT2[e] = w2[(o * 128 + i) * 27 + t];
  }
}

// ---- K_pvox (proven) ------------------------------------------------------
__global__ void calc_pvox(const float* __restrict__ coords, int* __restrict__ pvox) {
  int t = blockIdx.x * 256 + threadIdx.x;  // < 4*16384
  if (t >= 4 * NPTS) return;
  const float* cp = coords + (size_t)t * 3;
  int ix = min(max((int)floorf(cp[0] * 32.f), 0), 31);
  int iy = min(max((int)floorf(cp[1] * 32.f), 0), 31);
  int iz = min(max((int)floorf(cp[2] * 32.f), 0), 31);
  pvox[t] = (ix * 32 + iy) * 32 + iz;
}

// ---- K_scatter (proven) ---------------------------------------------------
__global__ void __launch_bounds__(256)
scatter_feats(const float* __restrict__ features, const int* __restrict__ pvox,
              float* __restrict__ Gsum, float* __restrict__ Gcnt) {
  size_t t = (size_t)blockIdx.x * 256 + threadIdx.x;  // < 4 * 2^20
  int n  = (int)(t & 16383);
  int ci = (int)((t >> 14) & 63);
  int bi = (int)(t >> 20);
  int v = pvox[bi * NPTS + n];
  float val = features[t];  // features flat [b][ci][n] index == t
  atomicAdd(&Gsum[((size_t)bi * R3 + v) * 64 + ci], val);
  if (ci == 0) atomicAdd(&Gcnt[bi * R3 + v], 1.f);
}

// ---- K_finalize (proven) --------------------------------------------------
__global__ void __launch_bounds__(256)
finalize_grid(float* __restrict__ Gsum, const float* __restrict__ Gcnt) {
  size_t t = (size_t)blockIdx.x * 256 + threadIdx.x;  // < 4*32768*64
  float c = Gcnt[t >> 6];
  Gsum[t] = Gsum[t] / fmaxf(c, 1.f);
}

// ---- BISECT PROBE: conv with IDENTICAL staging/taps/epilogue to the MFMA --
// kernel, but MFMA+fragment block replaced by scalar dots over the SAME
// staged LDS bytes, filling acc[] at the exact (co,vox) slots the epilogue's
// C/D formula expects. wT fp32 [t][ci][co] (proven layout).
template<int CIN, int OMODE>
__global__ void __launch_bounds__(256)
conv_scalar(const float* __restrict__ X, const float* __restrict__ wT,
            const float* __restrict__ bias, const float* __restrict__ gamma,
            const float* __restrict__ beta, u16* __restrict__ Yb,
            float* __restrict__ Yf) {
  constexpr int CINP = CIN + 8;            // identical LDS layout
  constexpr int ROWS = 68;                 // 2 y-lines x 34 z-halo
  __shared__ __align__(16) u16 Xh[ROWS * CINP];
  __shared__ __align__(16) u16 Xl[ROWS * CINP];

  const int tid = threadIdx.x;
  const int wave = tid >> 6, lane = tid & 63;
  const int l31 = lane & 31, lh = lane >> 5;
  const int cobase = wave * 32;

  const int bi = blockIdx.x >> 9;
  const int rem = blockIdx.x & 511;
  const int x = rem >> 4, y0 = (rem & 15) << 1;

  float acc0[16], acc1[16];
#pragma unroll
  for (int i = 0; i < 16; ++i) { acc0[i] = 0.f; acc1[i] = 0.f; }

  constexpr int CH4 = CIN / 4;
  for (int g = 0; g < 9; ++g) {
    __syncthreads();
    const int dx = g / 3 - 1, dy = g % 3 - 1;
    const int xs = x + dx;
    for (int c = tid; c < ROWS * CH4; c += 256) {   // identical staging
      int rr = c / CH4, k = (c % CH4) * 4;
      float4 val = make_float4(0.f, 0.f, 0.f, 0.f);
      int vy = (rr >= 34) ? 1 : 0;
      int zz = rr - vy * 34 - 1;           // z' in [-1,32]
      int ys = y0 + vy + dy;
      if (xs >= 0 && xs < 32 && ys >= 0 && ys < 32 && zz >= 0 && zz < 32)
        val = *(const float4*)(X + ((size_t)bi * R3 + (size_t)((xs * 32 + ys) * 32 + zz)) * CIN + k);
      ushort4 hh, ll;
      split2(val.x, hh.x, ll.x);
      split2(val.y, hh.y, ll.y);
      split2(val.z, hh.z, ll.z);
      split2(val.w, hh.w, ll.w);
      *(ushort4*)(&Xh[rr * CINP + k]) = hh;
      *(ushort4*)(&Xl[rr * CINP + k]) = ll;
    }
    __syncthreads();
    for (int dz = 0; dz < 3; ++dz) {
      const int t = g * 3 + dz;
      const int o0 = (l31 + dz) * CINP;          // y-line 0, same rows as MFMA reads
      const int o1 = (34 + l31 + dz) * CINP;     // y-line 1
      const float* wrow = wT + (size_t)t * CIN * 128 + cobase + 4 * lh;
      for (int ci = 0; ci < CIN; ++ci) {
        float x0 = b2f(Xh[o0 + ci]) + b2f(Xl[o0 + ci]);
        float x1 = b2f(Xh[o1 + ci]) + b2f(Xl[o1 + ci]);
        const float* wp = wrow + (size_t)ci * 128;
#pragma unroll
        for (int Q = 0; Q < 4; ++Q) {
          // reg r=4Q+i <-> co = cobase + 8Q + 4lh + i  (the epilogue's col formula)
          float4 w4 = *(const float4*)(wp + 8 * Q);
          acc0[4 * Q + 0] = fmaf(w4.x, x0, acc0[4 * Q + 0]);
          acc0[4 * Q + 1] = fmaf(w4.y, x0, acc0[4 * Q + 1]);
          acc0[4 * Q + 2] = fmaf(w4.z, x0, acc0[4 * Q + 2]);
          acc0[4 * Q + 3] = fmaf(w4.w, x0, acc0[4 * Q + 3]);
          acc1[4 * Q + 0] = fmaf(w4.x, x1, acc1[4 * Q + 0]);
          acc1[4 * Q + 1] = fmaf(w4.y, x1, acc1[4 * Q + 1]);
          acc1[4 * Q + 2] = fmaf(w4.z, x1, acc1[4 * Q + 2]);
          acc1[4 * Q + 3] = fmaf(w4.w, x1, acc1[4 * Q + 3]);
        }
      }
    }
  }

  // ---- epilogue: byte-identical to the MFMA kernel ----
  float v0[16], v1[16];
#pragma unroll
  for (int r = 0; r < 16; ++r) {
    int col = (r & 3) + 8 * (r >> 2) + 4 * lh;
    float bb = bias[cobase + col];
    v0[r] = acc0[r] + bb;
    v1[r] = acc1[r] + bb;
  }

  size_t row0 = (size_t)bi * R3 + (size_t)((x * 32 + y0) * 32 + l31);
  size_t row1 = row0 + 32;  // (y0+1) line

#pragma unroll
  for (int cg = 0; cg < 2; ++cg) {
    float* v = cg ? v1 : v0;
#pragma unroll
    for (int gs = 0; gs < 2; ++gs) {   // regs 0..7 -> group 2w, 8..15 -> 2w+1
      float s = 0.f, sq = 0.f;
#pragma unroll
      for (int r = gs * 8; r < gs * 8 + 8; ++r) { s += v[r]; sq += v[r] * v[r]; }
      s += __shfl_xor(s, 32);
      sq += __shfl_xor(sq, 32);
      float mu = s * 0.0625f;
      float var = sq * 0.0625f - mu * mu;
      float rs = rsqrtf(var + 1e-5f);
#pragma unroll
      for (int r = gs * 8; r < gs * 8 + 8; ++r) {
        int co = cobase + (r & 3) + 8 * (r >> 2) + 4 * lh;
        float xn = (v[r] - mu) * rs * gamma[co] + beta[co];
        v[r] = silu(xn);
      }
    }
  }

#pragma unroll
  for (int cg = 0; cg < 2; ++cg) {
    float* v = cg ? v1 : v0;
    size_t row = cg ? row1 : row0;
    if (OMODE == 0) {
      float* yp = Yf + row * 128 + cobase + 4 * lh;
#pragma unroll
      for (int q = 0; q < 4; ++q)
        *(float4*)(yp + 8 * q) = make_float4(v[4 * q], v[4 * q + 1], v[4 * q + 2], v[4 * q + 3]);
    } else {
      u16* yp = Yb + row * 128 + cobase + 4 * lh;
#pragma unroll
      for (int q = 0; q < 4; ++q) {   // regs 4q..4q+3 = co 8q+4lh+0..3 (contig)
        uint2 d;
        d.x = (unsigned)f2b(v[4 * q]) | ((unsigned)f2b(v[4 * q + 1]) << 16);
        d.y = (unsigned)f2b(v[4 * q + 2]) | ((unsigned)f2b(v[4 * q + 3]) << 16);
        *(uint2*)(yp + 8 * q) = d;
      }
    }
  }
}

// ---- K_mlp (proven) -------------------------------------------------------
__global__ void __launch_bounds__(128)
mlp_naive(const float* __restrict__ features, const float* __restrict__ mw,
          const float* __restrict__ mb, u16* __restrict__ pf) {
  const int co = threadIdx.x;          // 0..127
  const int n = blockIdx.x & 16383;
  const int bi = blockIdx.x >> 14;
  float acc = mb[co];
  const float* fp = features + (size_t)bi * 64 * NPTS + n;
  const float* wp = mw + co * 64;
  for (int i = 0; i < 64; ++i) acc = fmaf(fp[(size_t)i * NPTS], wp[i], acc);
  pf[((size_t)bi * NPTS + n) * 128 + co] = f2b(acc);
}

// ---- K_stats (proven) -----------------------------------------------------
__global__ void __launch_bounds__(256)
point_stats(const u16* __restrict__ pf, float* __restrict__ stats) {
  __shared__ float sl[256], ql[256];
  const int bi = blockIdx.x >> 3;
  const int g = blockIdx.x & 7;
  float s = 0.f, sq = 0.f;
  for (int n = threadIdx.x; n < NPTS; n += 256) {
    const u16* pp = pf + ((size_t)bi * NPTS + n) * 128 + g * 16;
#pragma unroll
    for (int j = 0; j < 16; ++j) {
      float v = b2f(pp[j]);
      s += v; sq = fmaf(v, v, sq);
    }
  }
  sl[threadIdx.x] = s; ql[threadIdx.x] = sq;
  __syncthreads();
  for (int off = 128; off > 0; off >>= 1) {
    if (threadIdx.x < off) {
      sl[threadIdx.x] += sl[threadIdx.x + off];
      ql[threadIdx.x] += ql[threadIdx.x + off];
    }
    __syncthreads();
  }
  if (threadIdx.x == 0) {
    stats[(bi * 8 + g) * 2 + 0] = sl[0];
    stats[(bi * 8 + g) * 2 + 1] = ql[0];
  }
}

// ---- K_final (proven) -----------------------------------------------------
__global__ void __launch_bounds__(256)
final_fuse(const float* __restrict__ coords, const u16* __restrict__ H,
           const u16* __restrict__ pf, const float* __restrict__ stats,
           const float* __restrict__ gg, const float* __restrict__ gb,
           float* __restrict__ out) {
  __shared__ float trans[64][130];
  const int tid = threadIdx.x;
  const int wave = tid >> 6, lane = tid & 63;
  const int bi = blockIdx.x >> 8;
  const int p0 = (blockIdx.x & 255) << 6;
  const int co = lane * 2;
  const int grp = co >> 4;
  const float cntInv = 1.f / (16.f * 16384.f);
  float S  = stats[(bi * 8 + grp) * 2 + 0];
  float SS = stats[(bi * 8 + grp) * 2 + 1];
  float mu = S * cntInv;
  float var = SS * cntInv - mu * mu;
  float rs = rsqrtf(var + 1e-5f);
  float g0 = gg[co], g1 = gg[co + 1], b0 = gb[co], b1 = gb[co + 1];

  for (int pi = 0; pi < 16; ++pi) {
    int pl = wave * 16 + pi;
    int p = p0 + pl;
    const float* cp = coords + ((size_t)bi * NPTS + p) * 3;
    float cx = cp[0] * 32.f, cy = cp[1] * 32.f, cz = cp[2] * 32.f;
    float fx = floorf(cx), fy = floorf(cy), fz = floorf(cz);
    int ix = min(max((int)fx, 0), 31);
    int iy = min(max((int)fy, 0), 31);
    int iz = min(max((int)fz, 0), 31);
    float rx = cx - fx, ry = cy - fy, rz = cz - fz;
    int hx = min(ix + 1, 31), hy = min(iy + 1, 31), hz = min(iz + 1, 31);
    float a0 = 0.f, a1 = 0.f;
#pragma unroll
    for (int k = 0; k < 8; ++k) {
      int xb = k >> 2, yb = (k >> 1) & 1, zb = k & 1;
      float w = (xb ? rx : 1.f - rx) * (yb ? ry : 1.f - ry) * (zb ? rz : 1.f - rz);
      int vi = ((xb ? hx : ix) * 32 + (yb ? hy : iy)) * 32 + (zb ? hz : iz);
      unsigned hv = *(const unsigned*)(H + ((size_t)bi * R3 + vi) * 128 + co);
      a0 += w * b2f((u16)(hv & 0xffff));
      a1 += w * b2f((u16)(hv >> 16));
    }
    unsigned pv = *(const unsigned*)(pf + ((size_t)bi * NPTS + p) * 128 + co);
    float q0 = (b2f((u16)(pv & 0xffff)) - mu) * rs * g0 + b0;
    float q1 = (b2f((u16)(pv >> 16)) - mu) * rs * g1 + b1;
    trans[pl][co]     = silu(q0) + a0;
    trans[pl][co + 1] = silu(q1) + a1;
  }
  __syncthreads();
  for (int e = tid; e < 8192; e += 256) {
    int c = e >> 6, pp = e & 63;
    out[((size_t)bi * 128 + c) * NPTS + p0 + pp] = trans[pp][c];
  }
}

// ---- host -----------------------------------------------------------------
extern "C" void kernel_launch(void* const* d_in, const int* in_sizes, int n_in,
                              void* d_out, int out_size, void* d_ws, size_t ws_size,
                              hipStream_t stream) {
  const float* coords   = (const float*)d_in[0];
  const float* features = (const float*)d_in[1];
  const float* conv1_w  = (const float*)d_in[2];
  const float* conv1_b  = (const float*)d_in[3];
  const float* gn1_g    = (const float*)d_in[4];
  const float* gn1_b    = (const float*)d_in[5];
  const float* conv2_w  = (const float*)d_in[6];
  const float* conv2_b  = (const float*)d_in[7];
  const float* gn2_g    = (const float*)d_in[8];
  const float* gn2_b    = (const float*)d_in[9];
  const float* mlp_w    = (const float*)d_in[10];
  const float* mlp_b    = (const float*)d_in[11];
  const float* gnp_g    = (const float*)d_in[12];
  const float* gnp_b    = (const float*)d_in[13];

  char* ws = (char*)d_ws;
  // layout (bytes):
  float* Gsum = (float*)(ws + 0);            // 33554432 fp32 [b][vox][64] -> X1 in place; H bf16 aliases
  u16*   H    = (u16*)(ws + 0);              // 33554432 bf16 [b][vox][128]
  float* X2   = (float*)(ws + 33554432);     // 67108864 fp32 [b][vox][128] -> 100663296
  float* Gcnt = (float*)(ws + 100663296);    // 524288   -> 101187584
  float* stats = (float*)(ws + 101187584);   // 4096     -> 101191680
  int*   pvox = (int*)(ws + 101191680);      // 262144   -> 101453824
  u16*   pf   = (u16*)(ws + 101453824);      // 16777216 -> 118231040
  float* wT1  = (float*)(ws + 118231040);    // 884736   -> 119115776
  float* wT2  = (float*)(ws + 119115776);    // 1769472  -> 120885248 (~120.9 MB)

  hipMemsetAsync(ws, 0, 33554432, stream);                    // Gsum
  hipMemsetAsync(ws + 100663296, 0, 524288 + 4096, stream);   // Gcnt + stats

  transform_w<<<(27 * 128 * 128 + 255) / 256, 256, 0, stream>>>(conv1_w, conv2_w, wT1, wT2);
  calc_pvox<<<(4 * NPTS + 255) / 256, 256, 0, stream>>>(coords, pvox);
  scatter_feats<<<16384, 256, 0, stream>>>(features, pvox, Gsum, Gcnt);
  finalize_grid<<<32768, 256, 0, stream>>>(Gsum, Gcnt);
  conv_scalar<64, 0><<<2048, 256, 0, stream>>>(
      Gsum, wT1, conv1_b, gn1_g, gn1_b, (u16*)nullptr, X2);
  mlp_naive<<<4 * NPTS, 128, 0, stream>>>(features, mlp_w, mlp_b, pf);
  point_stats<<<32, 256, 0, stream>>>(pf, stats);
  conv_scalar<128, 1><<<2048, 256, 0, stream>>>(
      X2, wT2, conv2_b, gn2_g, gn2_b, H, (float*)nullptr);
  final_fuse<<<1024, 256, 0, stream>>>(coords, H, pf, stats, gnp_g, gnp_b,
                                       (float*)d_out);
}

// Round 8
// 1415.880 us; speedup vs baseline: 10.0307x; 3.9341x over previous
//
#include <hip/hip_runtime.h>

typedef unsigned short u16;
typedef __attribute__((ext_vector_type(8))) short s16x8;
typedef __attribute__((ext_vector_type(4))) float f32x4;

#define R3 32768
#define NPTS 16384

__device__ __forceinline__ float b2f(u16 u) {
  union { unsigned int i; float f; } v; v.i = ((unsigned int)u) << 16; return v.f;
}
__device__ __forceinline__ u16 f2b(float f) {
  union { float f; unsigned int i; } v; v.f = f;
  unsigned int x = v.i;
  return (u16)((x + 0x7fffu + ((x >> 16) & 1u)) >> 16);
}
__device__ __forceinline__ void split2(float x, u16& h, u16& l) {
  h = f2b(x); l = f2b(x - b2f(h));
}
__device__ __forceinline__ float silu(float x) {
  return x / (1.f + __expf(-x));
}

// ---- K0: conv weights -> hi/lo bf16 [tap][co][ci] -------------------------
__global__ void convert_weights(const float* __restrict__ w1, const float* __restrict__ w2,
                                u16* __restrict__ Wh1, u16* __restrict__ Wl1,
                                u16* __restrict__ Wh2, u16* __restrict__ Wl2) {
  int e = blockIdx.x * 256 + threadIdx.x;
  if (e < 27 * 128 * 64) {
    int t = e / (128 * 64), co = (e / 64) % 128, ci = e % 64;
    split2(w1[(co * 64 + ci) * 27 + t], Wh1[e], Wl1[e]);
  }
  if (e < 27 * 128 * 128) {
    int t = e / (128 * 128), co = (e / 128) % 128, ci = e % 128;
    split2(w2[(co * 128 + ci) * 27 + t], Wh2[e], Wl2[e]);
  }
}

// ---- K_pvox (proven) ------------------------------------------------------
__global__ void calc_pvox(const float* __restrict__ coords, int* __restrict__ pvox) {
  int t = blockIdx.x * 256 + threadIdx.x;  // < 4*16384
  if (t >= 4 * NPTS) return;
  const float* cp = coords + (size_t)t * 3;
  int ix = min(max((int)floorf(cp[0] * 32.f), 0), 31);
  int iy = min(max((int)floorf(cp[1] * 32.f), 0), 31);
  int iz = min(max((int)floorf(cp[2] * 32.f), 0), 31);
  pvox[t] = (ix * 32 + iy) * 32 + iz;
}

// ---- K_scatter (proven) ---------------------------------------------------
__global__ void __launch_bounds__(256)
scatter_feats(const float* __restrict__ features, const int* __restrict__ pvox,
              float* __restrict__ Gsum, float* __restrict__ Gcnt) {
  size_t t = (size_t)blockIdx.x * 256 + threadIdx.x;  // < 4 * 2^20
  int n  = (int)(t & 16383);
  int ci = (int)((t >> 14) & 63);
  int bi = (int)(t >> 20);
  int v = pvox[bi * NPTS + n];
  float val = features[t];  // features flat [b][ci][n] index == t
  atomicAdd(&Gsum[((size_t)bi * R3 + v) * 64 + ci], val);
  if (ci == 0) atomicAdd(&Gcnt[bi * R3 + v], 1.f);
}

// ---- K_finalize (proven) --------------------------------------------------
__global__ void __launch_bounds__(256)
finalize_grid(float* __restrict__ Gsum, const float* __restrict__ Gcnt) {
  size_t t = (size_t)blockIdx.x * 256 + threadIdx.x;  // < 4*32768*64
  float c = Gcnt[t >> 6];
  Gsum[t] = Gsum[t] / fmaxf(c, 1.f);
}

// ---- conv, split-bf16 MFMA with RUNTIME-CALIBRATED C/D layout -------------
// Calibration (assumption-minimal: only A-row = lane&15, B-col = lane&15):
//   D1 = MFMA(A=lane-id, B=ones)  -> D1[m][n] = 32*(m+1)  (any k-map, any C/D)
//   D2 = MFMA(A=ones, B=lane-id)  -> D2[m][n] = 32*(n+1)
// Each lane decodes (m,n) per acc reg, scatters acc into LDS at decoded
// (co,z); fixed clean mapping does bias+GN+SiLU+store (no layout deps).
template<int CIN, int OMODE>
__global__ void __launch_bounds__(256)
conv_mfma16(const float* __restrict__ X, const u16* __restrict__ Wh, const u16* __restrict__ Wl,
            const float* __restrict__ bias, const float* __restrict__ gamma,
            const float* __restrict__ beta, u16* __restrict__ Yb, float* __restrict__ Yf) {
  constexpr int CINP = CIN + 8;            // row stride 144B / 272B
  constexpr int ROWS = 68;                 // 2 y-lines x 34 z-halo
  constexpr int KS = CIN / 32;             // K=32 per MFMA
  __shared__ __align__(16) u16 Xh[ROWS * CINP];
  __shared__ __align__(16) u16 Xl[ROWS * CINP];
  __shared__ float ldsW[4 * 32 * 33];      // per-wave [co 32][z 32+1] scratch

  const int tid = threadIdx.x;
  const int wave = tid >> 6, lane = tid & 63;
  const int l15 = lane & 15, q = lane >> 4;
  const int cobase = wave * 32;

  const int bi = blockIdx.x >> 9;
  const int rem = blockIdx.x & 511;
  const int x = rem >> 4, y0 = (rem & 15) << 1;

  // ---- runtime C/D calibration ----
  u16 oneb = f2b(1.0f), lidb = f2b((float)(l15 + 1));
  s16x8 vone, vlid;
#pragma unroll
  for (int e = 0; e < 8; ++e) { vone[e] = (short)oneb; vlid[e] = (short)lidb; }
  f32x4 z4 = {0.f, 0.f, 0.f, 0.f};
  f32x4 d1 = __builtin_amdgcn_mfma_f32_16x16x32_bf16(vlid, vone, z4, 0, 0, 0);
  f32x4 d2 = __builtin_amdgcn_mfma_f32_16x16x32_bf16(vone, vlid, z4, 0, 0, 0);
  int mdec[4], ndec[4];
#pragma unroll
  for (int r = 0; r < 4; ++r) {
    mdec[r] = (int)(d1[r] * 0.03125f + 0.5f) - 1;   // D1/32 - 1
    ndec[r] = (int)(d2[r] * 0.03125f + 0.5f) - 1;   // D2/32 - 1
  }

  f32x4 acc[2][2][2];  // [ct][vt][line]
#pragma unroll
  for (int a = 0; a < 2; ++a)
#pragma unroll
    for (int b = 0; b < 2; ++b)
#pragma unroll
      for (int c = 0; c < 2; ++c) acc[a][b][c] = (f32x4){0.f, 0.f, 0.f, 0.f};

  constexpr int CH4 = CIN / 4;
  for (int g = 0; g < 9; ++g) {
    __syncthreads();
    const int dx = g / 3 - 1, dy = g % 3 - 1;
    const int xs = x + dx;
    for (int c = tid; c < ROWS * CH4; c += 256) {   // staging: PROVEN
      int rr = c / CH4, k = (c % CH4) * 4;
      float4 val = make_float4(0.f, 0.f, 0.f, 0.f);
      int vy = (rr >= 34) ? 1 : 0;
      int zz = rr - vy * 34 - 1;           // z' in [-1,32]
      int ys = y0 + vy + dy;
      if (xs >= 0 && xs < 32 && ys >= 0 && ys < 32 && zz >= 0 && zz < 32)
        val = *(const float4*)(X + ((size_t)bi * R3 + (size_t)((xs * 32 + ys) * 32 + zz)) * CIN + k);
      ushort4 hh, ll;
      split2(val.x, hh.x, ll.x);
      split2(val.y, hh.y, ll.y);
      split2(val.z, hh.z, ll.z);
      split2(val.w, hh.w, ll.w);
      *(ushort4*)(&Xh[rr * CINP + k]) = hh;
      *(ushort4*)(&Xl[rr * CINP + k]) = ll;
    }
    __syncthreads();
    for (int dz = 0; dz < 3; ++dz) {
      const int t = g * 3 + dz;
#pragma unroll
      for (int kb = 0; kb < KS; ++kb) {
        const int ko = kb * 32 + q * 8;
        s16x8 ah[2], al[2], bh[2][2], bl[2][2];
#pragma unroll
        for (int ct = 0; ct < 2; ++ct) {
          size_t wo = ((size_t)(t * 128 + cobase + ct * 16 + l15)) * CIN + ko;
          ah[ct] = *(const s16x8*)(Wh + wo);
          al[ct] = *(const s16x8*)(Wl + wo);
        }
#pragma unroll
        for (int vt = 0; vt < 2; ++vt) {
          int r0 = (vt * 16 + l15 + dz) * CINP + ko;        // y-line 0
          int r1 = (34 + vt * 16 + l15 + dz) * CINP + ko;   // y-line 1
          bh[vt][0] = *(const s16x8*)(&Xh[r0]);
          bl[vt][0] = *(const s16x8*)(&Xl[r0]);
          bh[vt][1] = *(const s16x8*)(&Xh[r1]);
          bl[vt][1] = *(const s16x8*)(&Xl[r1]);
        }
#pragma unroll
        for (int ct = 0; ct < 2; ++ct)
#pragma unroll
          for (int vt = 0; vt < 2; ++vt)
#pragma unroll
            for (int ln = 0; ln < 2; ++ln) {
              acc[ct][vt][ln] = __builtin_amdgcn_mfma_f32_16x16x32_bf16(
                  ah[ct], bh[vt][ln], acc[ct][vt][ln], 0, 0, 0);
              acc[ct][vt][ln] = __builtin_amdgcn_mfma_f32_16x16x32_bf16(
                  ah[ct], bl[vt][ln], acc[ct][vt][ln], 0, 0, 0);
              acc[ct][vt][ln] = __builtin_amdgcn_mfma_f32_16x16x32_bf16(
                  al[ct], bh[vt][ln], acc[ct][vt][ln], 0, 0, 0);
            }
      }
    }
  }

  // ---- epilogue: layout-agnostic via decoded scatter through LDS ----------
  const int half = lane >> 5, zl = lane & 31;
  const int wbase = wave * (32 * 33);
  for (int ln = 0; ln < 2; ++ln) {
    __syncthreads();   // protect per-wave scratch between ln passes
#pragma unroll
    for (int ct = 0; ct < 2; ++ct)
#pragma unroll
      for (int vt = 0; vt < 2; ++vt)
#pragma unroll
        for (int r = 0; r < 4; ++r)
          ldsW[wbase + (ct * 16 + mdec[r]) * 33 + (vt * 16 + ndec[r])] = acc[ct][vt][ln][r];
    __syncthreads();
    // clean fixed mapping: this lane = voxel z=zl, channels co0..co0+15
    const int co0 = cobase + half * 16;
    float v[16];
#pragma unroll
    for (int j = 0; j < 16; ++j)
      v[j] = ldsW[wbase + (half * 16 + j) * 33 + zl] + bias[co0 + j];
    float mu = 0.f;
#pragma unroll
    for (int j = 0; j < 16; ++j) mu += v[j];
    mu *= 0.0625f;
    float var = 0.f;
#pragma unroll
    for (int j = 0; j < 16; ++j) { float d = v[j] - mu; var = fmaf(d, d, var); }
    var *= 0.0625f;
    float rs = rsqrtf(var + 1e-5f);
#pragma unroll
    for (int j = 0; j < 16; ++j) {
      float xn = (v[j] - mu) * rs * gamma[co0 + j] + beta[co0 + j];
      v[j] = silu(xn);
    }
    size_t row = (size_t)bi * R3 + (size_t)((x * 32 + y0 + ln) * 32 + zl);
    if (OMODE == 0) {
      float* yp = Yf + row * 128 + co0;
#pragma unroll
      for (int k = 0; k < 4; ++k)
        *(float4*)(yp + 4 * k) = make_float4(v[4 * k], v[4 * k + 1], v[4 * k + 2], v[4 * k + 3]);
    } else {
      u16 outv[16];
#pragma unroll
      for (int j = 0; j < 16; ++j) outv[j] = f2b(v[j]);
      u16* yp = Yb + row * 128 + co0;
      *(uint4*)(yp)     = *(uint4*)(outv);
      *(uint4*)(yp + 8) = *(uint4*)(outv + 8);
    }
  }
}

// ---- K_mlp (proven) -------------------------------------------------------
__global__ void __launch_bounds__(128)
mlp_naive(const float* __restrict__ features, const float* __restrict__ mw,
          const float* __restrict__ mb, u16* __restrict__ pf) {
  const int co = threadIdx.x;          // 0..127
  const int n = blockIdx.x & 16383;
  const int bi = blockIdx.x >> 14;
  float acc = mb[co];
  const float* fp = features + (size_t)bi * 64 * NPTS + n;
  const float* wp = mw + co * 64;
  for (int i = 0; i < 64; ++i) acc = fmaf(fp[(size_t)i * NPTS], wp[i], acc);
  pf[((size_t)bi * NPTS + n) * 128 + co] = f2b(acc);
}

// ---- K_stats (proven) -----------------------------------------------------
__global__ void __launch_bounds__(256)
point_stats(const u16* __restrict__ pf, float* __restrict__ stats) {
  __shared__ float sl[256], ql[256];
  const int bi = blockIdx.x >> 3;
  const int g = blockIdx.x & 7;
  float s = 0.f, sq = 0.f;
  for (int n = threadIdx.x; n < NPTS; n += 256) {
    const u16* pp = pf + ((size_t)bi * NPTS + n) * 128 + g * 16;
#pragma unroll
    for (int j = 0; j < 16; ++j) {
      float v = b2f(pp[j]);
      s += v; sq = fmaf(v, v, sq);
    }
  }
  sl[threadIdx.x] = s; ql[threadIdx.x] = sq;
  __syncthreads();
  for (int off = 128; off > 0; off >>= 1) {
    if (threadIdx.x < off) {
      sl[threadIdx.x] += sl[threadIdx.x + off];
      ql[threadIdx.x] += ql[threadIdx.x + off];
    }
    __syncthreads();
  }
  if (threadIdx.x == 0) {
    stats[(bi * 8 + g) * 2 + 0] = sl[0];
    stats[(bi * 8 + g) * 2 + 1] = ql[0];
  }
}

// ---- K_final (proven) -----------------------------------------------------
__global__ void __launch_bounds__(256)
final_fuse(const float* __restrict__ coords, const u16* __restrict__ H,
           const u16* __restrict__ pf, const float* __restrict__ stats,
           const float* __restrict__ gg, const float* __restrict__ gb,
           float* __restrict__ out) {
  __shared__ float trans[64][130];
  const int tid = threadIdx.x;
  const int wave = tid >> 6, lane = tid & 63;
  const int bi = blockIdx.x >> 8;
  const int p0 = (blockIdx.x & 255) << 6;
  const int co = lane * 2;
  const int grp = co >> 4;
  const float cntInv = 1.f / (16.f * 16384.f);
  float S  = stats[(bi * 8 + grp) * 2 + 0];
  float SS = stats[(bi * 8 + grp) * 2 + 1];
  float mu = S * cntInv;
  float var = SS * cntInv - mu * mu;
  float rs = rsqrtf(var + 1e-5f);
  float g0 = gg[co], g1 = gg[co + 1], b0 = gb[co], b1 = gb[co + 1];

  for (int pi = 0; pi < 16; ++pi) {
    int pl = wave * 16 + pi;
    int p = p0 + pl;
    const float* cp = coords + ((size_t)bi * NPTS + p) * 3;
    float cx = cp[0] * 32.f, cy = cp[1] * 32.f, cz = cp[2] * 32.f;
    float fx = floorf(cx), fy = floorf(cy), fz = floorf(cz);
    int ix = min(max((int)fx, 0), 31);
    int iy = min(max((int)fy, 0), 31);
    int iz = min(max((int)fz, 0), 31);
    float rx = cx - fx, ry = cy - fy, rz = cz - fz;
    int hx = min(ix + 1, 31), hy = min(iy + 1, 31), hz = min(iz + 1, 31);
    float a0 = 0.f, a1 = 0.f;
#pragma unroll
    for (int k = 0; k < 8; ++k) {
      int xb = k >> 2, yb = (k >> 1) & 1, zb = k & 1;
      float w = (xb ? rx : 1.f - rx) * (yb ? ry : 1.f - ry) * (zb ? rz : 1.f - rz);
      int vi = ((xb ? hx : ix) * 32 + (yb ? hy : iy)) * 32 + (zb ? hz : iz);
      unsigned hv = *(const unsigned*)(H + ((size_t)bi * R3 + vi) * 128 + co);
      a0 += w * b2f((u16)(hv & 0xffff));
      a1 += w * b2f((u16)(hv >> 16));
    }
    unsigned pv = *(const unsigned*)(pf + ((size_t)bi * NPTS + p) * 128 + co);
    float q0 = (b2f((u16)(pv & 0xffff)) - mu) * rs * g0 + b0;
    float q1 = (b2f((u16)(pv >> 16)) - mu) * rs * g1 + b1;
    trans[pl][co]     = silu(q0) + a0;
    trans[pl][co + 1] = silu(q1) + a1;
  }
  __syncthreads();
  for (int e = tid; e < 8192; e += 256) {
    int c = e >> 6, pp = e & 63;
    out[((size_t)bi * 128 + c) * NPTS + p0 + pp] = trans[pp][c];
  }
}

// ---- host -----------------------------------------------------------------
extern "C" void kernel_launch(void* const* d_in, const int* in_sizes, int n_in,
                              void* d_out, int out_size, void* d_ws, size_t ws_size,
                              hipStream_t stream) {
  const float* coords   = (const float*)d_in[0];
  const float* features = (const float*)d_in[1];
  const float* conv1_w  = (const float*)d_in[2];
  const float* conv1_b  = (const float*)d_in[3];
  const float* gn1_g    = (const float*)d_in[4];
  const float* gn1_b    = (const float*)d_in[5];
  const float* conv2_w  = (const float*)d_in[6];
  const float* conv2_b  = (const float*)d_in[7];
  const float* gn2_g    = (const float*)d_in[8];
  const float* gn2_b    = (const float*)d_in[9];
  const float* mlp_w    = (const float*)d_in[10];
  const float* mlp_b    = (const float*)d_in[11];
  const float* gnp_g    = (const float*)d_in[12];
  const float* gnp_b    = (const float*)d_in[13];

  char* ws = (char*)d_ws;
  // layout (bytes):
  float* Gsum = (float*)(ws + 0);            // 33554432 fp32 [b][vox][64] -> X1 in place; H bf16 aliases
  u16*   H    = (u16*)(ws + 0);              // 33554432 bf16 [b][vox][128]
  float* X2   = (float*)(ws + 33554432);     // 67108864 fp32 [b][vox][128] -> 100663296
  float* Gcnt = (float*)(ws + 100663296);    // 524288   -> 101187584
  float* stats = (float*)(ws + 101187584);   // 4096     -> 101191680
  int*   pvox = (int*)(ws + 101191680);      // 262144   -> 101453824
  u16*   pf   = (u16*)(ws + 101453824);      // 16777216 -> 118231040
  u16*   Wh1  = (u16*)(ws + 118231040);      // 442368   -> 118673408
  u16*   Wl1  = (u16*)(ws + 118673408);      // 442368   -> 119115776
  u16*   Wh2  = (u16*)(ws + 119115776);      // 884736   -> 120000512
  u16*   Wl2  = (u16*)(ws + 120000512);      // 884736   -> 120885248 (~120.9 MB)

  hipMemsetAsync(ws, 0, 33554432, stream);                    // Gsum
  hipMemsetAsync(ws + 100663296, 0, 524288 + 4096, stream);   // Gcnt + stats

  convert_weights<<<(27 * 128 * 128 + 255) / 256, 256, 0, stream>>>(
      conv1_w, conv2_w, Wh1, Wl1, Wh2, Wl2);
  calc_pvox<<<(4 * NPTS + 255) / 256, 256, 0, stream>>>(coords, pvox);
  scatter_feats<<<16384, 256, 0, stream>>>(features, pvox, Gsum, Gcnt);
  finalize_grid<<<32768, 256, 0, stream>>>(Gsum, Gcnt);
  conv_mfma16<64, 0><<<2048, 256, 0, stream>>>(
      Gsum, Wh1, Wl1, conv1_b, gn1_g, gn1_b, (u16*)nullptr, X2);
  mlp_naive<<<4 * NPTS, 128, 0, stream>>>(features, mlp_w, mlp_b, pf);
  point_stats<<<32, 256, 0, stream>>>(pf, stats);
  conv_mfma16<128, 1><<<2048, 256, 0, stream>>>(
      X2, Wh2, Wl2, conv2_b, gn2_g, gn2_b, H, (float*)nullptr);
  final_fuse<<<1024, 256, 0, stream>>>(coords, H, pf, stats, gnp_g, gnp_b,
                                       (float*)d_out);
}

// Round 9
// 1312.582 us; speedup vs baseline: 10.8201x; 1.0787x over previous
//
#include <hip/hip_runtime.h>

typedef unsigned short u16;
typedef __attribute__((ext_vector_type(8))) short s16x8;
typedef __attribute__((ext_vector_type(4))) float f32x4;

#define R3 32768
#define NPTS 16384

__device__ __forceinline__ float b2f(u16 u) {
  union { unsigned int i; float f; } v; v.i = ((unsigned int)u) << 16; return v.f;
}
__device__ __forceinline__ u16 f2b(float f) {
  union { float f; unsigned int i; } v; v.f = f;
  unsigned int x = v.i;
  return (u16)((x + 0x7fffu + ((x >> 16) & 1u)) >> 16);
}
__device__ __forceinline__ void split2(float x, u16& h, u16& l) {
  h = f2b(x); l = f2b(x - b2f(h));
}
__device__ __forceinline__ float silu(float x) {
  return x / (1.f + __expf(-x));
}

// ---- K0: conv weights -> hi/lo bf16 [tap][co][ci] -------------------------
__global__ void convert_weights(const float* __restrict__ w1, const float* __restrict__ w2,
                                u16* __restrict__ Wh1, u16* __restrict__ Wl1,
                                u16* __restrict__ Wh2, u16* __restrict__ Wl2) {
  int e = blockIdx.x * 256 + threadIdx.x;
  if (e < 27 * 128 * 64) {
    int t = e / (128 * 64), co = (e / 64) % 128, ci = e % 64;
    split2(w1[(co * 64 + ci) * 27 + t], Wh1[e], Wl1[e]);
  }
  if (e < 27 * 128 * 128) {
    int t = e / (128 * 128), co = (e / 128) % 128, ci = e % 128;
    split2(w2[(co * 128 + ci) * 27 + t], Wh2[e], Wl2[e]);
  }
}

// ---- K_pvox (proven) ------------------------------------------------------
__global__ void calc_pvox(const float* __restrict__ coords, int* __restrict__ pvox) {
  int t = blockIdx.x * 256 + threadIdx.x;  // < 4*16384
  if (t >= 4 * NPTS) return;
  const float* cp = coords + (size_t)t * 3;
  int ix = min(max((int)floorf(cp[0] * 32.f), 0), 31);
  int iy = min(max((int)floorf(cp[1] * 32.f), 0), 31);
  int iz = min(max((int)floorf(cp[2] * 32.f), 0), 31);
  pvox[t] = (ix * 32 + iy) * 32 + iz;
}

// ---- K_scatter (proven) ---------------------------------------------------
__global__ void __launch_bounds__(256)
scatter_feats(const float* __restrict__ features, const int* __restrict__ pvox,
              float* __restrict__ Gsum, float* __restrict__ Gcnt) {
  size_t t = (size_t)blockIdx.x * 256 + threadIdx.x;  // < 4 * 2^20
  int n  = (int)(t & 16383);
  int ci = (int)((t >> 14) & 63);
  int bi = (int)(t >> 20);
  int v = pvox[bi * NPTS + n];
  float val = features[t];  // features flat [b][ci][n] index == t
  atomicAdd(&Gsum[((size_t)bi * R3 + v) * 64 + ci], val);
  if (ci == 0) atomicAdd(&Gcnt[bi * R3 + v], 1.f);
}

// ---- K_finalize: X1 = bf16(Gsum / max(cnt,1)) -----------------------------
__global__ void __launch_bounds__(256)
finalize_grid(const float* __restrict__ Gsum, const float* __restrict__ Gcnt,
              u16* __restrict__ X1) {
  size_t t = (size_t)blockIdx.x * 256 + threadIdx.x;  // < 4*32768*64
  float c = Gcnt[t >> 6];
  X1[t] = f2b(Gsum[t] / fmaxf(c, 1.f));
}

// ---- conv: X bf16 [b][vox][CIN], W split hi/lo bf16 [tap][128co][ci] ------
// 2-term MFMA: (Wh + Wl)·X, fp32 accum. Runtime-calibrated C/D decode
// (PROVEN r8). Epilogue scratch aliases the X LDS buffer (dead by then).
// Output: per-voxel GN(16)+SiLU -> bf16 [b][vox][128].
template<int CIN>
__global__ void __launch_bounds__(256)
conv_mfma16(const u16* __restrict__ X, const u16* __restrict__ Wh, const u16* __restrict__ Wl,
            const float* __restrict__ bias, const float* __restrict__ gamma,
            const float* __restrict__ beta, u16* __restrict__ Yb) {
  constexpr int CINP = CIN + 8;            // row stride (odd x 16B)
  constexpr int ROWS = 68;                 // 2 y-lines x 34 z-halo
  constexpr int KS = CIN / 32;             // K=32 per MFMA
  constexpr int XBYTES = ROWS * CINP * 2;
  constexpr int SBYTES = 4 * 32 * 33 * 4;
  __shared__ __align__(16) char ldsbuf[(XBYTES > SBYTES) ? XBYTES : SBYTES];
  u16* Xs = (u16*)ldsbuf;
  float* ldsW = (float*)ldsbuf;            // valid only after X reads drained

  const int tid = threadIdx.x;
  const int wave = tid >> 6, lane = tid & 63;
  const int l15 = lane & 15, q = lane >> 4;
  const int cobase = wave * 32;

  const int bi = blockIdx.x >> 9;
  const int rem = blockIdx.x & 511;
  const int x = rem >> 4, y0 = (rem & 15) << 1;

  // ---- runtime C/D calibration (PROVEN r8) ----
  u16 oneb = f2b(1.0f), lidb = f2b((float)(l15 + 1));
  s16x8 vone, vlid;
#pragma unroll
  for (int e = 0; e < 8; ++e) { vone[e] = (short)oneb; vlid[e] = (short)lidb; }
  f32x4 z4 = {0.f, 0.f, 0.f, 0.f};
  f32x4 d1 = __builtin_amdgcn_mfma_f32_16x16x32_bf16(vlid, vone, z4, 0, 0, 0);
  f32x4 d2 = __builtin_amdgcn_mfma_f32_16x16x32_bf16(vone, vlid, z4, 0, 0, 0);
  int mdec[4], ndec[4];
#pragma unroll
  for (int r = 0; r < 4; ++r) {
    mdec[r] = (int)(d1[r] * 0.03125f + 0.5f) - 1;
    ndec[r] = (int)(d2[r] * 0.03125f + 0.5f) - 1;
  }

  f32x4 acc[2][2][2];  // [ct][vt][line]
#pragma unroll
  for (int a = 0; a < 2; ++a)
#pragma unroll
    for (int b = 0; b < 2; ++b)
#pragma unroll
      for (int c = 0; c < 2; ++c) acc[a][b][c] = (f32x4){0.f, 0.f, 0.f, 0.f};

  constexpr int CH8 = CIN / 8;
  for (int g = 0; g < 9; ++g) {
    __syncthreads();
    const int dx = g / 3 - 1, dy = g % 3 - 1;
    const int xs = x + dx;
    for (int c = tid; c < ROWS * CH8; c += 256) {   // pure uint4 copy staging
      int rr = c / CH8, k = (c % CH8) * 8;
      uint4 val; val.x = val.y = val.z = val.w = 0u;
      int vy = (rr >= 34) ? 1 : 0;
      int zz = rr - vy * 34 - 1;           // z' in [-1,32]
      int ys = y0 + vy + dy;
      if (xs >= 0 && xs < 32 && ys >= 0 && ys < 32 && zz >= 0 && zz < 32)
        val = *(const uint4*)(X + ((size_t)bi * R3 + (size_t)((xs * 32 + ys) * 32 + zz)) * CIN + k);
      *(uint4*)(&Xs[rr * CINP + k]) = val;
    }
    __syncthreads();
    for (int dz = 0; dz < 3; ++dz) {
      const int t = g * 3 + dz;
#pragma unroll
      for (int kb = 0; kb < KS; ++kb) {
        const int ko = kb * 32 + q * 8;
        s16x8 ah[2], al[2], bb[2][2];
#pragma unroll
        for (int ct = 0; ct < 2; ++ct) {
          size_t wo = ((size_t)(t * 128 + cobase + ct * 16 + l15)) * CIN + ko;
          ah[ct] = *(const s16x8*)(Wh + wo);
          al[ct] = *(const s16x8*)(Wl + wo);
        }
#pragma unroll
        for (int vt = 0; vt < 2; ++vt) {
          bb[vt][0] = *(const s16x8*)(&Xs[(vt * 16 + l15 + dz) * CINP + ko]);
          bb[vt][1] = *(const s16x8*)(&Xs[(34 + vt * 16 + l15 + dz) * CINP + ko]);
        }
#pragma unroll
        for (int ct = 0; ct < 2; ++ct)
#pragma unroll
          for (int vt = 0; vt < 2; ++vt)
#pragma unroll
            for (int ln = 0; ln < 2; ++ln) {
              acc[ct][vt][ln] = __builtin_amdgcn_mfma_f32_16x16x32_bf16(
                  ah[ct], bb[vt][ln], acc[ct][vt][ln], 0, 0, 0);
              acc[ct][vt][ln] = __builtin_amdgcn_mfma_f32_16x16x32_bf16(
                  al[ct], bb[vt][ln], acc[ct][vt][ln], 0, 0, 0);
            }
      }
    }
  }

  // ---- epilogue: layout-agnostic decoded scatter through LDS (PROVEN r8) --
  const int half = lane >> 5, zl = lane & 31;
  const int wbase = wave * (32 * 33);
  for (int ln = 0; ln < 2; ++ln) {
    __syncthreads();   // also drains last Xs reads -> safe to overwrite
#pragma unroll
    for (int ct = 0; ct < 2; ++ct)
#pragma unroll
      for (int vt = 0; vt < 2; ++vt)
#pragma unroll
        for (int r = 0; r < 4; ++r)
          ldsW[wbase + (ct * 16 + mdec[r]) * 33 + (vt * 16 + ndec[r])] = acc[ct][vt][ln][r];
    __syncthreads();
    const int co0 = cobase + half * 16;
    float v[16];
#pragma unroll
    for (int j = 0; j < 16; ++j)
      v[j] = ldsW[wbase + (half * 16 + j) * 33 + zl] + bias[co0 + j];
    float mu = 0.f;
#pragma unroll
    for (int j = 0; j < 16; ++j) mu += v[j];
    mu *= 0.0625f;
    float var = 0.f;
#pragma unroll
    for (int j = 0; j < 16; ++j) { float d = v[j] - mu; var = fmaf(d, d, var); }
    var *= 0.0625f;
    float rs = rsqrtf(var + 1e-5f);
#pragma unroll
    for (int j = 0; j < 16; ++j) {
      float xn = (v[j] - mu) * rs * gamma[co0 + j] + beta[co0 + j];
      v[j] = silu(xn);
    }
    size_t row = (size_t)bi * R3 + (size_t)((x * 32 + y0 + ln) * 32 + zl);
    u16 outv[16];
#pragma unroll
    for (int j = 0; j < 16; ++j) outv[j] = f2b(v[j]);
    u16* yp = Yb + row * 128 + co0;
    *(uint4*)(yp)     = *(uint4*)(outv);
    *(uint4*)(yp + 8) = *(uint4*)(outv + 8);
  }
}

// ---- K_mlp (proven) -------------------------------------------------------
__global__ void __launch_bounds__(128)
mlp_naive(const float* __restrict__ features, const float* __restrict__ mw,
          const float* __restrict__ mb, u16* __restrict__ pf) {
  const int co = threadIdx.x;          // 0..127
  const int n = blockIdx.x & 16383;
  const int bi = blockIdx.x >> 14;
  float acc = mb[co];
  const float* fp = features + (size_t)bi * 64 * NPTS + n;
  const float* wp = mw + co * 64;
  for (int i = 0; i < 64; ++i) acc = fmaf(fp[(size_t)i * NPTS], wp[i], acc);
  pf[((size_t)bi * NPTS + n) * 128 + co] = f2b(acc);
}

// ---- K_stats (proven) -----------------------------------------------------
__global__ void __launch_bounds__(256)
point_stats(const u16* __restrict__ pf, float* __restrict__ stats) {
  __shared__ float sl[256], ql[256];
  const int bi = blockIdx.x >> 3;
  const int g = blockIdx.x & 7;
  float s = 0.f, sq = 0.f;
  for (int n = threadIdx.x; n < NPTS; n += 256) {
    const u16* pp = pf + ((size_t)bi * NPTS + n) * 128 + g * 16;
#pragma unroll
    for (int j = 0; j < 16; ++j) {
      float v = b2f(pp[j]);
      s += v; sq = fmaf(v, v, sq);
    }
  }
  sl[threadIdx.x] = s; ql[threadIdx.x] = sq;
  __syncthreads();
  for (int off = 128; off > 0; off >>= 1) {
    if (threadIdx.x < off) {
      sl[threadIdx.x] += sl[threadIdx.x + off];
      ql[threadIdx.x] += ql[threadIdx.x + off];
    }
    __syncthreads();
  }
  if (threadIdx.x == 0) {
    stats[(bi * 8 + g) * 2 + 0] = sl[0];
    stats[(bi * 8 + g) * 2 + 1] = ql[0];
  }
}

// ---- K_final (proven) -----------------------------------------------------
__global__ void __launch_bounds__(256)
final_fuse(const float* __restrict__ coords, const u16* __restrict__ H,
           const u16* __restrict__ pf, const float* __restrict__ stats,
           const float* __restrict__ gg, const float* __restrict__ gb,
           float* __restrict__ out) {
  __shared__ float trans[64][130];
  const int tid = threadIdx.x;
  const int wave = tid >> 6, lane = tid & 63;
  const int bi = blockIdx.x >> 8;
  const int p0 = (blockIdx.x & 255) << 6;
  const int co = lane * 2;
  const int grp = co >> 4;
  const float cntInv = 1.f / (16.f * 16384.f);
  float S  = stats[(bi * 8 + grp) * 2 + 0];
  float SS = stats[(bi * 8 + grp) * 2 + 1];
  float mu = S * cntInv;
  float var = SS * cntInv - mu * mu;
  float rs = rsqrtf(var + 1e-5f);
  float g0 = gg[co], g1 = gg[co + 1], b0 = gb[co], b1 = gb[co + 1];

  for (int pi = 0; pi < 16; ++pi) {
    int pl = wave * 16 + pi;
    int p = p0 + pl;
    const float* cp = coords + ((size_t)bi * NPTS + p) * 3;
    float cx = cp[0] * 32.f, cy = cp[1] * 32.f, cz = cp[2] * 32.f;
    float fx = floorf(cx), fy = floorf(cy), fz = floorf(cz);
    int ix = min(max((int)fx, 0), 31);
    int iy = min(max((int)fy, 0), 31);
    int iz = min(max((int)fz, 0), 31);
    float rx = cx - fx, ry = cy - fy, rz = cz - fz;
    int hx = min(ix + 1, 31), hy = min(iy + 1, 31), hz = min(iz + 1, 31);
    float a0 = 0.f, a1 = 0.f;
#pragma unroll
    for (int k = 0; k < 8; ++k) {
      int xb = k >> 2, yb = (k >> 1) & 1, zb = k & 1;
      float w = (xb ? rx : 1.f - rx) * (yb ? ry : 1.f - ry) * (zb ? rz : 1.f - rz);
      int vi = ((xb ? hx : ix) * 32 + (yb ? hy : iy)) * 32 + (zb ? hz : iz);
      unsigned hv = *(const unsigned*)(H + ((size_t)bi * R3 + vi) * 128 + co);
      a0 += w * b2f((u16)(hv & 0xffff));
      a1 += w * b2f((u16)(hv >> 16));
    }
    unsigned pv = *(const unsigned*)(pf + ((size_t)bi * NPTS + p) * 128 + co);
    float q0 = (b2f((u16)(pv & 0xffff)) - mu) * rs * g0 + b0;
    float q1 = (b2f((u16)(pv >> 16)) - mu) * rs * g1 + b1;
    trans[pl][co]     = silu(q0) + a0;
    trans[pl][co + 1] = silu(q1) + a1;
  }
  __syncthreads();
  for (int e = tid; e < 8192; e += 256) {
    int c = e >> 6, pp = e & 63;
    out[((size_t)bi * 128 + c) * NPTS + p0 + pp] = trans[pp][c];
  }
}

// ---- host -----------------------------------------------------------------
extern "C" void kernel_launch(void* const* d_in, const int* in_sizes, int n_in,
                              void* d_out, int out_size, void* d_ws, size_t ws_size,
                              hipStream_t stream) {
  const float* coords   = (const float*)d_in[0];
  const float* features = (const float*)d_in[1];
  const float* conv1_w  = (const float*)d_in[2];
  const float* conv1_b  = (const float*)d_in[3];
  const float* gn1_g    = (const float*)d_in[4];
  const float* gn1_b    = (const float*)d_in[5];
  const float* conv2_w  = (const float*)d_in[6];
  const float* conv2_b  = (const float*)d_in[7];
  const float* gn2_g    = (const float*)d_in[8];
  const float* gn2_b    = (const float*)d_in[9];
  const float* mlp_w    = (const float*)d_in[10];
  const float* mlp_b    = (const float*)d_in[11];
  const float* gnp_g    = (const float*)d_in[12];
  const float* gnp_b    = (const float*)d_in[13];

  char* ws = (char*)d_ws;
  // layout (bytes):
  float* Gsum = (float*)(ws + 0);            // 33554432 fp32 [b][vox][64]; H bf16 aliases after conv1
  u16*   H    = (u16*)(ws + 0);              // 33554432 bf16 [b][vox][128]
  u16*   X1   = (u16*)(ws + 33554432);       // 16777216 bf16 [b][vox][64]  -> 50331648
  u16*   X2   = (u16*)(ws + 50331648);       // 33554432 bf16 [b][vox][128] -> 83886080
  float* Gcnt = (float*)(ws + 83886080);     // 524288   -> 84410368
  float* stats = (float*)(ws + 84410368);    // 4096     -> 84414464
  int*   pvox = (int*)(ws + 84414464);       // 262144   -> 84676608
  u16*   pf   = (u16*)(ws + 84676608);       // 16777216 -> 101453824
  u16*   Wh1  = (u16*)(ws + 101453824);      // 442368   -> 101896192
  u16*   Wl1  = (u16*)(ws + 101896192);      // 442368   -> 102338560
  u16*   Wh2  = (u16*)(ws + 102338560);      // 884736   -> 103223296
  u16*   Wl2  = (u16*)(ws + 103223296);      // 884736   -> 104108032 (~104 MB)

  hipMemsetAsync(ws, 0, 33554432, stream);                   // Gsum
  hipMemsetAsync(ws + 83886080, 0, 524288 + 4096, stream);   // Gcnt + stats

  convert_weights<<<(27 * 128 * 128 + 255) / 256, 256, 0, stream>>>(
      conv1_w, conv2_w, Wh1, Wl1, Wh2, Wl2);
  calc_pvox<<<(4 * NPTS + 255) / 256, 256, 0, stream>>>(coords, pvox);
  scatter_feats<<<16384, 256, 0, stream>>>(features, pvox, Gsum, Gcnt);
  finalize_grid<<<32768, 256, 0, stream>>>(Gsum, Gcnt, X1);
  conv_mfma16<64><<<2048, 256, 0, stream>>>(
      X1, Wh1, Wl1, conv1_b, gn1_g, gn1_b, X2);
  mlp_naive<<<4 * NPTS, 128, 0, stream>>>(features, mlp_w, mlp_b, pf);
  point_stats<<<32, 256, 0, stream>>>(pf, stats);
  conv_mfma16<128><<<2048, 256, 0, stream>>>(
      X2, Wh2, Wl2, conv2_b, gn2_g, gn2_b, H);
  final_fuse<<<1024, 256, 0, stream>>>(coords, H, pf, stats, gnp_g, gnp_b,
                                       (float*)d_out);
}

// Round 10
// 866.695 us; speedup vs baseline: 16.3867x; 1.5145x over previous
//
#include <hip/hip_runtime.h>

typedef unsigned short u16;
typedef __attribute__((ext_vector_type(8))) short s16x8;
typedef __attribute__((ext_vector_type(4))) float f32x4;

#define R3 32768
#define NPTS 16384

__device__ __forceinline__ float b2f(u16 u) {
  union { unsigned int i; float f; } v; v.i = ((unsigned int)u) << 16; return v.f;
}
__device__ __forceinline__ u16 f2b(float f) {
  union { float f; unsigned int i; } v; v.f = f;
  unsigned int x = v.i;
  return (u16)((x + 0x7fffu + ((x >> 16) & 1u)) >> 16);
}
__device__ __forceinline__ void split2(float x, u16& h, u16& l) {
  h = f2b(x); l = f2b(x - b2f(h));
}
__device__ __forceinline__ float silu(float x) {
  return x / (1.f + __expf(-x));
}

// ---- K0: weights -> hi/lo bf16. conv: [tap][co][ci]; mlp: [co][ci] --------
__global__ void convert_weights(const float* __restrict__ w1, const float* __restrict__ w2,
                                const float* __restrict__ wm,
                                u16* __restrict__ Wh1, u16* __restrict__ Wl1,
                                u16* __restrict__ Wh2, u16* __restrict__ Wl2,
                                u16* __restrict__ Whm, u16* __restrict__ Wlm) {
  int e = blockIdx.x * 256 + threadIdx.x;
  if (e < 27 * 128 * 64) {
    int t = e / (128 * 64), co = (e / 64) % 128, ci = e % 64;
    split2(w1[(co * 64 + ci) * 27 + t], Wh1[e], Wl1[e]);
  }
  if (e < 27 * 128 * 128) {
    int t = e / (128 * 128), co = (e / 128) % 128, ci = e % 128;
    split2(w2[(co * 128 + ci) * 27 + t], Wh2[e], Wl2[e]);
  }
  if (e < 128 * 64) split2(wm[e], Whm[e], Wlm[e]);
}

// ---- K_pvox (proven) ------------------------------------------------------
__global__ void calc_pvox(const float* __restrict__ coords, int* __restrict__ pvox) {
  int t = blockIdx.x * 256 + threadIdx.x;  // < 4*16384
  if (t >= 4 * NPTS) return;
  const float* cp = coords + (size_t)t * 3;
  int ix = min(max((int)floorf(cp[0] * 32.f), 0), 31);
  int iy = min(max((int)floorf(cp[1] * 32.f), 0), 31);
  int iz = min(max((int)floorf(cp[2] * 32.f), 0), 31);
  pvox[t] = (ix * 32 + iy) * 32 + iz;
}

// ---- K_scatter (proven) ---------------------------------------------------
__global__ void __launch_bounds__(256)
scatter_feats(const float* __restrict__ features, const int* __restrict__ pvox,
              float* __restrict__ Gsum, float* __restrict__ Gcnt) {
  size_t t = (size_t)blockIdx.x * 256 + threadIdx.x;  // < 4 * 2^20
  int n  = (int)(t & 16383);
  int ci = (int)((t >> 14) & 63);
  int bi = (int)(t >> 20);
  int v = pvox[bi * NPTS + n];
  float val = features[t];  // features flat [b][ci][n] index == t
  atomicAdd(&Gsum[((size_t)bi * R3 + v) * 64 + ci], val);
  if (ci == 0) atomicAdd(&Gcnt[bi * R3 + v], 1.f);
}

// ---- K_finalize: X1 = bf16(Gsum / max(cnt,1)) -----------------------------
__global__ void __launch_bounds__(256)
finalize_grid(const float* __restrict__ Gsum, const float* __restrict__ Gcnt,
              u16* __restrict__ X1) {
  size_t t = (size_t)blockIdx.x * 256 + threadIdx.x;  // < 4*32768*64
  float c = Gcnt[t >> 6];
  X1[t] = f2b(Gsum[t] / fmaxf(c, 1.f));
}

// ---- conv: X bf16 [b][vox][CIN], W split hi/lo bf16 [tap][128co][ci] ------
// 4 y-lines per block (128 output voxels). 2-term split MFMA, calibrated
// C/D decode (PROVEN r8/r9). Epilogue scratch aliases X LDS buffer.
template<int CIN>
__global__ void __launch_bounds__(256)
conv_mfma16(const u16* __restrict__ X, const u16* __restrict__ Wh, const u16* __restrict__ Wl,
            const float* __restrict__ bias, const float* __restrict__ gamma,
            const float* __restrict__ beta, u16* __restrict__ Yb) {
  constexpr int CINP = CIN + 8;            // row stride (odd x 16B)
  constexpr int ROWS = 136;                // 4 y-lines x 34 z-halo
  constexpr int KS = CIN / 32;
  constexpr int XBYTES = ROWS * CINP * 2;
  constexpr int SBYTES = 4 * 2 * 32 * 33 * 4;   // 4 waves x 2 lines x [32co][33z]
  __shared__ __align__(16) char ldsbuf[(XBYTES > SBYTES) ? XBYTES : SBYTES];
  u16* Xs = (u16*)ldsbuf;
  float* ldsW = (float*)ldsbuf;            // valid only after X reads drained

  const int tid = threadIdx.x;
  const int wave = tid >> 6, lane = tid & 63;
  const int l15 = lane & 15, q = lane >> 4;
  const int cobase = wave * 32;

  const int bi = blockIdx.x >> 8;
  const int rem = blockIdx.x & 255;
  const int x = rem >> 3, y0 = (rem & 7) << 2;

  // ---- runtime C/D calibration (PROVEN r8) ----
  u16 oneb = f2b(1.0f), lidb = f2b((float)(l15 + 1));
  s16x8 vone, vlid;
#pragma unroll
  for (int e = 0; e < 8; ++e) { vone[e] = (short)oneb; vlid[e] = (short)lidb; }
  f32x4 z4 = {0.f, 0.f, 0.f, 0.f};
  f32x4 d1 = __builtin_amdgcn_mfma_f32_16x16x32_bf16(vlid, vone, z4, 0, 0, 0);
  f32x4 d2 = __builtin_amdgcn_mfma_f32_16x16x32_bf16(vone, vlid, z4, 0, 0, 0);
  int mdec[4], ndec[4];
#pragma unroll
  for (int r = 0; r < 4; ++r) {
    mdec[r] = (int)(d1[r] * 0.03125f + 0.5f) - 1;
    ndec[r] = (int)(d2[r] * 0.03125f + 0.5f) - 1;
  }

  f32x4 acc[2][2][4];  // [ct][vt][line]
#pragma unroll
  for (int a = 0; a < 2; ++a)
#pragma unroll
    for (int b = 0; b < 2; ++b)
#pragma unroll
      for (int c = 0; c < 4; ++c) acc[a][b][c] = (f32x4){0.f, 0.f, 0.f, 0.f};

  constexpr int CH8 = CIN / 8;
  for (int g = 0; g < 9; ++g) {
    __syncthreads();
    const int dx = g / 3 - 1, dy = g % 3 - 1;
    const int xs = x + dx;
    for (int c = tid; c < ROWS * CH8; c += 256) {   // pure uint4 copy staging
      int rr = c / CH8, k = (c % CH8) * 8;
      uint4 val; val.x = val.y = val.z = val.w = 0u;
      int vy = rr / 34;                    // 0..3
      int zz = rr - vy * 34 - 1;           // z' in [-1,32]
      int ys = y0 + vy + dy;
      if (xs >= 0 && xs < 32 && ys >= 0 && ys < 32 && zz >= 0 && zz < 32)
        val = *(const uint4*)(X + ((size_t)bi * R3 + (size_t)((xs * 32 + ys) * 32 + zz)) * CIN + k);
      *(uint4*)(&Xs[rr * CINP + k]) = val;
    }
    __syncthreads();
    for (int dz = 0; dz < 3; ++dz) {
      const int t = g * 3 + dz;
#pragma unroll
      for (int kb = 0; kb < KS; ++kb) {
        const int ko = kb * 32 + q * 8;
        s16x8 ah[2], al[2], bb[2][4];
#pragma unroll
        for (int ct = 0; ct < 2; ++ct) {
          size_t wo = ((size_t)(t * 128 + cobase + ct * 16 + l15)) * CIN + ko;
          ah[ct] = *(const s16x8*)(Wh + wo);
          al[ct] = *(const s16x8*)(Wl + wo);
        }
#pragma unroll
        for (int vt = 0; vt < 2; ++vt)
#pragma unroll
          for (int ln = 0; ln < 4; ++ln)
            bb[vt][ln] = *(const s16x8*)(&Xs[(ln * 34 + vt * 16 + l15 + dz) * CINP + ko]);
#pragma unroll
        for (int ct = 0; ct < 2; ++ct)
#pragma unroll
          for (int vt = 0; vt < 2; ++vt)
#pragma unroll
            for (int ln = 0; ln < 4; ++ln) {
              acc[ct][vt][ln] = __builtin_amdgcn_mfma_f32_16x16x32_bf16(
                  ah[ct], bb[vt][ln], acc[ct][vt][ln], 0, 0, 0);
              acc[ct][vt][ln] = __builtin_amdgcn_mfma_f32_16x16x32_bf16(
                  al[ct], bb[vt][ln], acc[ct][vt][ln], 0, 0, 0);
            }
      }
    }
  }

  // ---- epilogue: decoded scatter through LDS, 2 lines per pass ------------
  const int half = lane >> 5, zl = lane & 31;
  for (int p = 0; p < 2; ++p) {
    __syncthreads();   // drains Xs reads -> safe to overwrite
#pragma unroll
    for (int l2 = 0; l2 < 2; ++l2)
#pragma unroll
      for (int ct = 0; ct < 2; ++ct)
#pragma unroll
        for (int vt = 0; vt < 2; ++vt)
#pragma unroll
          for (int r = 0; r < 4; ++r)
            ldsW[((wave * 2 + l2) * 32 + ct * 16 + mdec[r]) * 33 + vt * 16 + ndec[r]] =
                acc[ct][vt][2 * p + l2][r];
    __syncthreads();
    const int co0 = cobase + half * 16;
#pragma unroll
    for (int l2 = 0; l2 < 2; ++l2) {
      float v[16];
#pragma unroll
      for (int j = 0; j < 16; ++j)
        v[j] = ldsW[((wave * 2 + l2) * 32 + half * 16 + j) * 33 + zl] + bias[co0 + j];
      float mu = 0.f;
#pragma unroll
      for (int j = 0; j < 16; ++j) mu += v[j];
      mu *= 0.0625f;
      float var = 0.f;
#pragma unroll
      for (int j = 0; j < 16; ++j) { float d = v[j] - mu; var = fmaf(d, d, var); }
      var *= 0.0625f;
      float rs = rsqrtf(var + 1e-5f);
#pragma unroll
      for (int j = 0; j < 16; ++j) {
        float xn = (v[j] - mu) * rs * gamma[co0 + j] + beta[co0 + j];
        v[j] = silu(xn);
      }
      size_t row = (size_t)bi * R3 + (size_t)((x * 32 + y0 + 2 * p + l2) * 32 + zl);
      u16 outv[16];
#pragma unroll
      for (int j = 0; j < 16; ++j) outv[j] = f2b(v[j]);
      u16* yp = Yb + row * 128 + co0;
      *(uint4*)(yp)     = *(uint4*)(outv);
      *(uint4*)(yp + 8) = *(uint4*)(outv + 8);
    }
  }
}

// ---- K_mlp: MFMA 1x1 conv + fused global-GN stats -------------------------
// features fp32 [b][ci][n] -> staged bf16 [64pt][64ci+8]; W split hi/lo
// [128co][64ci]. pf bf16 [b][n][128] = W@f + bias (raw). stats atomicAdd.
__global__ void __launch_bounds__(256)
mlp_mfma(const float* __restrict__ features, const u16* __restrict__ Whm,
         const u16* __restrict__ Wlm, const float* __restrict__ mb,
         u16* __restrict__ pf, float* __restrict__ stats) {
  constexpr int XBYTES = 64 * 72 * 2;
  constexpr int SBYTES = 4 * 64 * 33 * 4;   // 4 waves x [64pt][32co+1]
  __shared__ __align__(16) char ldsbuf[(XBYTES > SBYTES) ? XBYTES : SBYTES];
  u16* Xs = (u16*)ldsbuf;
  float* ldsW = (float*)ldsbuf;

  const int tid = threadIdx.x;
  const int wave = tid >> 6, lane = tid & 63;
  const int l15 = lane & 15, q = lane >> 4;
  const int cobase = wave * 32;
  const int bi = blockIdx.x >> 8;
  const int n0 = (blockIdx.x & 255) << 6;

  // calibration (PROVEN r8)
  u16 oneb = f2b(1.0f), lidb = f2b((float)(l15 + 1));
  s16x8 vone, vlid;
#pragma unroll
  for (int e = 0; e < 8; ++e) { vone[e] = (short)oneb; vlid[e] = (short)lidb; }
  f32x4 z4 = {0.f, 0.f, 0.f, 0.f};
  f32x4 d1 = __builtin_amdgcn_mfma_f32_16x16x32_bf16(vlid, vone, z4, 0, 0, 0);
  f32x4 d2 = __builtin_amdgcn_mfma_f32_16x16x32_bf16(vone, vlid, z4, 0, 0, 0);
  int mdec[4], ndec[4];
#pragma unroll
  for (int r = 0; r < 4; ++r) {
    mdec[r] = (int)(d1[r] * 0.03125f + 0.5f) - 1;
    ndec[r] = (int)(d2[r] * 0.03125f + 0.5f) - 1;
  }

  // stage transpose: Xs[pt][ci]
  for (int e = tid; e < 4096; e += 256) {
    int ci = e >> 6, nn = e & 63;
    Xs[nn * 72 + ci] = f2b(features[((size_t)bi * 64 + ci) * NPTS + n0 + nn]);
  }
  __syncthreads();

  f32x4 acc[2][4];  // [ct][vt: 4 point-tiles of 16]
#pragma unroll
  for (int a = 0; a < 2; ++a)
#pragma unroll
    for (int b = 0; b < 4; ++b) acc[a][b] = (f32x4){0.f, 0.f, 0.f, 0.f};

#pragma unroll
  for (int kb = 0; kb < 2; ++kb) {
    const int ko = kb * 32 + q * 8;
    s16x8 ah[2], al[2], bb[4];
#pragma unroll
    for (int ct = 0; ct < 2; ++ct) {
      size_t wo = ((size_t)(cobase + ct * 16 + l15)) * 64 + ko;
      ah[ct] = *(const s16x8*)(Whm + wo);
      al[ct] = *(const s16x8*)(Wlm + wo);
    }
#pragma unroll
    for (int vt = 0; vt < 4; ++vt)
      bb[vt] = *(const s16x8*)(&Xs[(vt * 16 + l15) * 72 + ko]);
#pragma unroll
    for (int ct = 0; ct < 2; ++ct)
#pragma unroll
      for (int vt = 0; vt < 4; ++vt) {
        acc[ct][vt] = __builtin_amdgcn_mfma_f32_16x16x32_bf16(ah[ct], bb[vt], acc[ct][vt], 0, 0, 0);
        acc[ct][vt] = __builtin_amdgcn_mfma_f32_16x16x32_bf16(al[ct], bb[vt], acc[ct][vt], 0, 0, 0);
      }
  }

  // epilogue: decoded scatter -> ldsW[wave][pt][co32], then store + stats
  __syncthreads();
#pragma unroll
  for (int ct = 0; ct < 2; ++ct)
#pragma unroll
    for (int vt = 0; vt < 4; ++vt)
#pragma unroll
      for (int r = 0; r < 4; ++r)
        ldsW[(wave * 64 + vt * 16 + ndec[r]) * 33 + ct * 16 + mdec[r]] = acc[ct][vt][r];
  __syncthreads();

  float v[32];
  float s0 = 0.f, q0 = 0.f, s1 = 0.f, q1 = 0.f;
#pragma unroll
  for (int j = 0; j < 32; ++j) {
    v[j] = ldsW[(wave * 64 + lane) * 33 + j] + mb[cobase + j];
    if (j < 16) { s0 += v[j]; q0 = fmaf(v[j], v[j], q0); }
    else        { s1 += v[j]; q1 = fmaf(v[j], v[j], q1); }
  }
  u16 outv[32];
#pragma unroll
  for (int j = 0; j < 32; ++j) outv[j] = f2b(v[j]);
  u16* yp = pf + ((size_t)bi * NPTS + n0 + lane) * 128 + cobase;
#pragma unroll
  for (int k = 0; k < 4; ++k) *(uint4*)(yp + 8 * k) = *(uint4*)(outv + 8 * k);

#pragma unroll
  for (int off = 32; off > 0; off >>= 1) {
    s0 += __shfl_xor(s0, off); q0 += __shfl_xor(q0, off);
    s1 += __shfl_xor(s1, off); q1 += __shfl_xor(q1, off);
  }
  if (lane == 0) {
    atomicAdd(&stats[(bi * 8 + 2 * wave + 0) * 2 + 0], s0);
    atomicAdd(&stats[(bi * 8 + 2 * wave + 0) * 2 + 1], q0);
    atomicAdd(&stats[(bi * 8 + 2 * wave + 1) * 2 + 0], s1);
    atomicAdd(&stats[(bi * 8 + 2 * wave + 1) * 2 + 1], q1);
  }
}

// ---- K_final (proven) -----------------------------------------------------
__global__ void __launch_bounds__(256)
final_fuse(const float* __restrict__ coords, const u16* __restrict__ H,
           const u16* __restrict__ pf, const float* __restrict__ stats,
           const float* __restrict__ gg, const float* __restrict__ gb,
           float* __restrict__ out) {
  __shared__ float trans[64][130];
  const int tid = threadIdx.x;
  const int wave = tid >> 6, lane = tid & 63;
  const int bi = blockIdx.x >> 8;
  const int p0 = (blockIdx.x & 255) << 6;
  const int co = lane * 2;
  const int grp = co >> 4;
  const float cntInv = 1.f / (16.f * 16384.f);
  float S  = stats[(bi * 8 + grp) * 2 + 0];
  float SS = stats[(bi * 8 + grp) * 2 + 1];
  float mu = S * cntInv;
  float var = SS * cntInv - mu * mu;
  float rs = rsqrtf(var + 1e-5f);
  float g0 = gg[co], g1 = gg[co + 1], b0 = gb[co], b1 = gb[co + 1];

  for (int pi = 0; pi < 16; ++pi) {
    int pl = wave * 16 + pi;
    int p = p0 + pl;
    const float* cp = coords + ((size_t)bi * NPTS + p) * 3;
    float cx = cp[0] * 32.f, cy = cp[1] * 32.f, cz = cp[2] * 32.f;
    float fx = floorf(cx), fy = floorf(cy), fz = floorf(cz);
    int ix = min(max((int)fx, 0), 31);
    int iy = min(max((int)fy, 0), 31);
    int iz = min(max((int)fz, 0), 31);
    float rx = cx - fx, ry = cy - fy, rz = cz - fz;
    int hx = min(ix + 1, 31), hy = min(iy + 1, 31), hz = min(iz + 1, 31);
    float a0 = 0.f, a1 = 0.f;
#pragma unroll
    for (int k = 0; k < 8; ++k) {
      int xb = k >> 2, yb = (k >> 1) & 1, zb = k & 1;
      float w = (xb ? rx : 1.f - rx) * (yb ? ry : 1.f - ry) * (zb ? rz : 1.f - rz);
      int vi = ((xb ? hx : ix) * 32 + (yb ? hy : iy)) * 32 + (zb ? hz : iz);
      unsigned hv = *(const unsigned*)(H + ((size_t)bi * R3 + vi) * 128 + co);
      a0 += w * b2f((u16)(hv & 0xffff));
      a1 += w * b2f((u16)(hv >> 16));
    }
    unsigned pv = *(const unsigned*)(pf + ((size_t)bi * NPTS + p) * 128 + co);
    float q0 = (b2f((u16)(pv & 0xffff)) - mu) * rs * g0 + b0;
    float q1 = (b2f((u16)(pv >> 16)) - mu) * rs * g1 + b1;
    trans[pl][co]     = silu(q0) + a0;
    trans[pl][co + 1] = silu(q1) + a1;
  }
  __syncthreads();
  for (int e = tid; e < 8192; e += 256) {
    int c = e >> 6, pp = e & 63;
    out[((size_t)bi * 128 + c) * NPTS + p0 + pp] = trans[pp][c];
  }
}

// ---- host -----------------------------------------------------------------
extern "C" void kernel_launch(void* const* d_in, const int* in_sizes, int n_in,
                              void* d_out, int out_size, void* d_ws, size_t ws_size,
                              hipStream_t stream) {
  const float* coords   = (const float*)d_in[0];
  const float* features = (const float*)d_in[1];
  const float* conv1_w  = (const float*)d_in[2];
  const float* conv1_b  = (const float*)d_in[3];
  const float* gn1_g    = (const float*)d_in[4];
  const float* gn1_b    = (const float*)d_in[5];
  const float* conv2_w  = (const float*)d_in[6];
  const float* conv2_b  = (const float*)d_in[7];
  const float* gn2_g    = (const float*)d_in[8];
  const float* gn2_b    = (const float*)d_in[9];
  const float* mlp_w    = (const float*)d_in[10];
  const float* mlp_b    = (const float*)d_in[11];
  const float* gnp_g    = (const float*)d_in[12];
  const float* gnp_b    = (const float*)d_in[13];

  char* ws = (char*)d_ws;
  // layout (bytes):
  float* Gsum = (float*)(ws + 0);            // 33554432 fp32 [b][vox][64]; H bf16 aliases after conv1
  u16*   H    = (u16*)(ws + 0);              // 33554432 bf16 [b][vox][128]
  u16*   X1   = (u16*)(ws + 33554432);       // 16777216 bf16 [b][vox][64]  -> 50331648
  u16*   X2   = (u16*)(ws + 50331648);       // 33554432 bf16 [b][vox][128] -> 83886080
  float* Gcnt = (float*)(ws + 83886080);     // 524288   -> 84410368
  float* stats = (float*)(ws + 84410368);    // 4096     -> 84414464
  int*   pvox = (int*)(ws + 84414464);       // 262144   -> 84676608
  u16*   pf   = (u16*)(ws + 84676608);       // 16777216 -> 101453824
  u16*   Wh1  = (u16*)(ws + 101453824);      // 442368   -> 101896192
  u16*   Wl1  = (u16*)(ws + 101896192);      // 442368   -> 102338560
  u16*   Wh2  = (u16*)(ws + 102338560);      // 884736   -> 103223296
  u16*   Wl2  = (u16*)(ws + 103223296);      // 884736   -> 104108032
  u16*   Whm  = (u16*)(ws + 104108032);      // 16384    -> 104124416
  u16*   Wlm  = (u16*)(ws + 104124416);      // 16384    -> 104140800 (~104 MB)

  hipMemsetAsync(ws, 0, 33554432, stream);                   // Gsum
  hipMemsetAsync(ws + 83886080, 0, 524288 + 4096, stream);   // Gcnt + stats

  convert_weights<<<(27 * 128 * 128 + 255) / 256, 256, 0, stream>>>(
      conv1_w, conv2_w, mlp_w, Wh1, Wl1, Wh2, Wl2, Whm, Wlm);
  calc_pvox<<<(4 * NPTS + 255) / 256, 256, 0, stream>>>(coords, pvox);
  scatter_feats<<<16384, 256, 0, stream>>>(features, pvox, Gsum, Gcnt);
  finalize_grid<<<32768, 256, 0, stream>>>(Gsum, Gcnt, X1);
  conv_mfma16<64><<<1024, 256, 0, stream>>>(
      X1, Wh1, Wl1, conv1_b, gn1_g, gn1_b, X2);
  mlp_mfma<<<1024, 256, 0, stream>>>(features, Whm, Wlm, mlp_b, pf, stats);
  conv_mfma16<128><<<1024, 256, 0, stream>>>(
      X2, Wh2, Wl2, conv2_b, gn2_g, gn2_b, H);
  final_fuse<<<1024, 256, 0, stream>>>(coords, H, pf, stats, gnp_g, gnp_b,
                                       (float*)d_out);
}